// Round 8
// baseline (6268.855 us; speedup 1.0000x reference)
//
#include <hip/hip_runtime.h>
#include <math.h>

// B=128, T=512, D=64, H=512. 512 WGs = 64 dim-slices x 8 batch-groups (16 batches each).
// Gates via split-bf16 MFMA (3-term), weight B-frags in registers (6 MFMA waves: 3ct x 2 K-half).
// h exchange modes:
//   mode 2 (XCD-local + hist): group == physical XCD (HW_REG_XCC_ID + atomic rank; verified
//     round-robin in round 7). h publish = plain stores (L1 write-through -> local L2); h fetch =
//     plain cached loads of write-once buffers (never-read lines can't be L1-stale). Flags =
//     atomic fetch_add RMWs (no sc bits -> execute at the LOCAL L2 atomic unit; cannot be served
//     stale from L1). Poll reads via fetch_add(+0x10000) & 0xFFFF (non-idempotent => compiler
//     cannot demote to a cached load); arrivals via fetch_add(+1).
//   mode 1 (agent + hist): round-5/6 proven path — sc1 publishes, LLC flag polls, plain data loads.
//   mode 0 (agent + ring): round-4 proven path — sc1 everything, 2-buffer ring.
#define TB 512
#define NWG 512

typedef __attribute__((ext_vector_type(8))) short bf16x8;
typedef __attribute__((ext_vector_type(4))) float f32x4;
typedef unsigned long long u64;

// LDS float offsets. Bytes [0,32768) = A-frags (h staged, frag-linear; also B-build scratch at init).
#define PREP_F 8192      // [2kh][2slot][16 rows][17] = 1088 f32
#define XPRE_F 9280      // 24 x 17 (teacher x-dot r8,z8,n8)
#define ORED_F 9688      // 16 x 17 (out partials)
#define WOC_F  9960      // 512 (W_out column s)
#define WIH_F  10472     // 24 x 66 (W_ih slice rows)
#define SB_F   12056     // 96 biases ([80]=b_out[s])
#define XLAST_F 12152    // 16 (x last channel, AR)
#define MSK_F  12168     // 512 ints
#define ROLE_F 12680     // 4 ints (g, slice, localmode)
#define LDS_FLOATS 12688
#define LDS_BYTES (LDS_FLOATS * 4)   // 50752

#define GRP_BYTES 32768
#define STEP_BYTES (8 * GRP_BYTES)   // 256KB per step (8 groups)
#define DATA_OFF 4096
#define HIST_NEEDED ((unsigned long long)DATA_OFF + 513ull * STEP_BYTES)
#define FB_NEEDED   ((unsigned long long)DATA_OFF + 2ull * STEP_BYTES)

__device__ __forceinline__ unsigned rne16(float f) {
  unsigned u = __float_as_uint(f);
  return (u + 0x7FFFu + ((u >> 16) & 1u)) >> 16;
}
__device__ __forceinline__ float bfhilo(unsigned hh, unsigned hl) {
  return __uint_as_float(hh << 16) + __uint_as_float(hl << 16);
}

__global__ __launch_bounds__(TB, 4) void gru_persistent(
    const float* __restrict__ x, const float* __restrict__ tp, const int* __restrict__ mask,
    const float* __restrict__ W_ih, const float* __restrict__ W_hh,
    const float* __restrict__ b_ih, const float* __restrict__ b_hh,
    const float* __restrict__ W_out, const float* __restrict__ b_out,
    char* __restrict__ ws, float* __restrict__ out, int hist)
{
  extern __shared__ char smem[];
  float* LP = (float*)smem;
  int* MSK = (int*)&LP[MSK_F];
  volatile int* ROLE = (volatile int*)&LP[ROLE_F];
  const int tid = threadIdx.x;
  const int lane = tid & 63;
  const int wv   = tid >> 6;
  const int myct = wv >> 1, mykh = wv & 1;

  unsigned* flags = (unsigned*)ws;            // 8 groups x 64 words
  unsigned* reg   = (unsigned*)(ws + 2048);   // reg[0..7]=per-XCD count, reg[8]=total
  char* data = ws + DATA_OFF;

  // ---------------- registration: discover XCD placement ----------------
  if (tid == 0) {
    unsigned xcc = 0;
    asm volatile("s_getreg_b32 %0, hwreg(HW_REG_XCC_ID)" : "=s"(xcc));
    xcc &= 7u;
    unsigned rank = __hip_atomic_fetch_add(&reg[xcc], 1u, __ATOMIC_RELAXED, __HIP_MEMORY_SCOPE_AGENT);
    __hip_atomic_fetch_add(&reg[8], 1u, __ATOMIC_RELAXED, __HIP_MEMORY_SCOPE_AGENT);
    int cnt = 0;
    while (__hip_atomic_load(&reg[8], __ATOMIC_RELAXED, __HIP_MEMORY_SCOPE_AGENT) < (unsigned)NWG) {
      __builtin_amdgcn_s_sleep(8);
      if (++cnt > 2000000) break;   // escape hatch
    }
    int ok = 1;
    for (int i = 0; i < 8; ++i)
      ok &= (__hip_atomic_load(&reg[i], __ATOMIC_RELAXED, __HIP_MEMORY_SCOPE_AGENT) == 64u);
    ok &= (rank < 64u);
    ROLE[0] = ok ? (int)xcc : (int)(blockIdx.x & 7);
    ROLE[1] = ok ? (int)rank : (int)(blockIdx.x >> 3);
    ROLE[2] = ok;
  }
  __syncthreads();
  const int g = ROLE[0];
  const int s = ROLE[1];
  const int mode = (ROLE[2] && hist) ? 2 : (hist ? 1 : 0);
  const int bg0 = g * 16;
  const int j0  = 8 * s;

  // ---------------- init staging ----------------
  MSK[tid] = mask[tid];
  if (tid < 65) {
    for (int p = 0; p < 24; ++p) {
      int row = (p < 8) ? (j0 + p) : (p < 16) ? (512 + j0 + (p - 8)) : (1024 + j0 + (p - 16));
      LP[WIH_F + p * 66 + tid] = W_ih[(size_t)row * 65 + tid];
    }
  }
  LP[WOC_F + tid] = W_out[(size_t)tid * 64 + s];
  if (tid < 16) {
    int row = (tid < 8) ? (j0 + tid) : (512 + j0 + (tid - 8));
    const float* wi = W_ih + (size_t)row * 65;
    float bt = b_ih[row] + b_hh[row];
    float bp = 0.f;
    for (int d = 0; d < 64; ++d) bp = fmaf(wi[d], b_out[d], bp);
    LP[SB_F + tid]      = bt;        // teacher rz bias
    LP[SB_F + 16 + tid] = bt + bp;   // AR rz bias
    LP[SB_F + 32 + tid] = wi[64];    // xlast coef rz
  } else if (tid < 24) {
    int jj = tid - 16;
    int row = 1024 + j0 + jj;
    const float* wi = W_ih + (size_t)row * 65;
    float bp = 0.f;
    for (int d = 0; d < 64; ++d) bp = fmaf(wi[d], b_out[d], bp);
    LP[SB_F + 48 + jj] = b_hh[row];
    LP[SB_F + 56 + jj] = b_ih[row];
    LP[SB_F + 64 + jj] = b_ih[row] + bp;
    LP[SB_F + 72 + jj] = wi[64];
  }
  if (tid == 0) LP[SB_F + 80] = b_out[s];
  __syncthreads();

  // ---------------- build B-frags to registers, 3 passes via A-region scratch ----------------
  bf16x8 Bh[8], Bl[8];
  {
    unsigned short* bw16 = (unsigned short*)smem;
    for (int ct = 0; ct < 3; ++ct) {
      const int k = tid;
      const float* wo = W_out + (size_t)k * 64;
      for (int wr = 0; wr < 16; ++wr) {
        float w;
        if (ct == 1) {
          int row = (wr < 8) ? (j0 + wr) : (512 + j0 + wr - 8);
          w = W_hh[(size_t)row * 512 + k];
        } else if (ct == 0) {
          if (wr < 8) w = W_hh[(size_t)(1024 + j0 + wr) * 512 + k];
          else {
            const float* wrp = &LP[WIH_F + (16 + wr - 8) * 66];
            float a = 0.f;
#pragma unroll 8
            for (int d = 0; d < 64; ++d) a = fmaf(wrp[d], wo[d], a);
            w = a;
          }
        } else {
          int row = (wr < 8) ? (j0 + wr) : (512 + j0 + wr - 8);
          const float* wrp = &LP[WIH_F + wr * 66];
          float a = 0.f;
#pragma unroll 8
          for (int d = 0; d < 64; ++d) a = fmaf(wrp[d], wo[d], a);
          w = a + W_hh[(size_t)row * 512 + k];
        }
        unsigned wh = rne16(w);
        float resid = w - __uint_as_float(wh << 16);
        unsigned wl = rne16(resid);
        int base = (k >> 5) * 1024 + (wr | (((k >> 3) & 3) << 4)) * 16 + (k & 7) * 2;
        bw16[base >> 1] = (unsigned short)wh;
        bw16[(base + 16384) >> 1] = (unsigned short)wl;
      }
      __syncthreads();
      if (wv < 6 && myct == ct) {
#pragma unroll
        for (int i = 0; i < 8; ++i) {
          Bh[i] = *(const bf16x8*)(smem + (mykh * 8 + i) * 1024 + lane * 16);
          Bl[i] = *(const bf16x8*)(smem + 16384 + (mykh * 8 + i) * 1024 + lane * 16);
        }
      }
      __syncthreads();
    }
  }

  // ---------------- zero h0 (buffer 0) ----------------
  if (tid < 32) {
    const int b = tid & 15, term = tid >> 4;
    size_t off = (size_t)(term * 16 + (s >> 2)) * 1024 + (size_t)(b | ((s & 3) << 4)) * 16;
    u64* p = (u64*)(data + (size_t)g * GRP_BYTES + off);
    if (mode == 2) {
      *(volatile u64*)p = 0ull; *(volatile u64*)(p + 1) = 0ull;
    } else {
      __hip_atomic_store(p,     0ull, __ATOMIC_RELAXED, __HIP_MEMORY_SCOPE_AGENT);
      __hip_atomic_store(p + 1, 0ull, __ATOMIC_RELAXED, __HIP_MEMORY_SCOPE_AGENT);
    }
  }

  // teacher x-dot staging for step tt (h-independent; runs in barrier windows)
  auto stage_x = [&](int tt) {
    if (tt >= 512) return;
    if (MSK[tt] != 0) {
      if (tid < 384) {
        const int xr = tid >> 4, b = tid & 15;
        const float* wrow = &LP[WIH_F + xr * 66];
        size_t ti = (size_t)(bg0 + b) * 512 + tt;
        float del = tp[ti] - (tt > 0 ? tp[ti - 1] : 0.f);
        float xa = wrow[64] * del;
        const float4* x4 = (const float4*)(x + ti * 64);
#pragma unroll
        for (int d4 = 0; d4 < 16; ++d4) {
          float4 xv = x4[d4];
          xa = fmaf(wrow[d4 * 4 + 0], xv.x, xa);
          xa = fmaf(wrow[d4 * 4 + 1], xv.y, xa);
          xa = fmaf(wrow[d4 * 4 + 2], xv.z, xa);
          xa = fmaf(wrow[d4 * 4 + 3], xv.w, xa);
        }
        LP[XPRE_F + xr * 17 + b] = xa;
      }
    } else if (tid < 16) {
      LP[XLAST_F + tid] = x[((size_t)(bg0 + tid) * 512 + tt) * 64 + 63];
    }
  };

  unsigned* myflags = &flags[g * 64];
  // Arrival: mode2 = +1 RMW at LOCAL L2 (cumulative count); else absolute sc1 store to LLC.
  auto flag_put = [&](unsigned tgt) {
    if (mode == 2)
      __hip_atomic_fetch_add(&myflags[s], 1u, __ATOMIC_RELAXED, __HIP_MEMORY_SCOPE_WORKGROUP);
    else
      __hip_atomic_store(&myflags[s], tgt, __ATOMIC_RELAXED, __HIP_MEMORY_SCOPE_AGENT);
  };
  // Poll: mode2 = non-idempotent RMW (executes at local L2, returns old; low 16 bits = arrivals).
  auto flag_poll = [&](unsigned tgt) {
    int cnt = 0;
    while (true) {
      unsigned v;
      if (mode == 2)
        v = __hip_atomic_fetch_add(&myflags[lane], 0x10000u, __ATOMIC_RELAXED,
                                   __HIP_MEMORY_SCOPE_WORKGROUP) & 0xFFFFu;
      else
        v = __hip_atomic_load(&myflags[lane], __ATOMIC_RELAXED, __HIP_MEMORY_SCOPE_AGENT);
      if (__ballot(v < tgt) == 0ull) break;
      __builtin_amdgcn_s_sleep(1);
      if (++cnt > 500000) break;   // escape hatch: wrong answer instead of hang
    }
  };

  stage_x(0);
  // initial barrier: h0 zeros + stage_x(0) done group-wide
  asm volatile("s_waitcnt vmcnt(0)" ::: "memory");
  __syncthreads();
  if (tid == 0) flag_put(1u);
  if (wv == 7) flag_poll(1u);
  __syncthreads();

  const unsigned short* ah16 = (const unsigned short*)smem;

  for (int t = 0; t <= 512; ++t) {
    const bool last = (t == 512);
    const bool teacher = (!last) && (MSK[t] != 0);
    const int csel = teacher ? 1 : 2;
    const char* src = data + (size_t)(hist ? t : (t & 1)) * STEP_BYTES + (size_t)g * GRP_BYTES;

    // -------- phase A: fetch 32KB h(t) image into LDS (frag-linear identity copy) --------
    if (mode == 0) {
      u64 a0[4], a1[4];
#pragma unroll
      for (int i = 0; i < 4; ++i) {
        const u64* p = (const u64*)(src + (size_t)(i * 512 + tid) * 16);
        a0[i] = __hip_atomic_load(p,     __ATOMIC_RELAXED, __HIP_MEMORY_SCOPE_AGENT);
        a1[i] = __hip_atomic_load(p + 1, __ATOMIC_RELAXED, __HIP_MEMORY_SCOPE_AGENT);
      }
#pragma unroll
      for (int i = 0; i < 4; ++i) {
        u64* d = (u64*)(smem + (size_t)(i * 512 + tid) * 16);
        d[0] = a0[i]; d[1] = a1[i];
      }
    } else {
      uint4 v[4];
#pragma unroll
      for (int i = 0; i < 4; ++i) v[i] = *(const uint4*)(src + (size_t)(i * 512 + tid) * 16);
#pragma unroll
      for (int i = 0; i < 4; ++i) *(uint4*)(smem + (size_t)(i * 512 + tid) * 16) = v[i];
    }
    __syncthreads();   // sync A

    // -------- MFMA (waves 0-5): ct0 always, ct1 teacher, ct2 AR; K-half = mykh --------
    if (!last && wv < 6 && (myct == 0 || myct == csel)) {
      f32x4 acc0 = {0.f, 0.f, 0.f, 0.f};
      f32x4 acc1 = {0.f, 0.f, 0.f, 0.f};
      f32x4 acc2 = {0.f, 0.f, 0.f, 0.f};
      f32x4 acc3 = {0.f, 0.f, 0.f, 0.f};
#pragma unroll
      for (int i = 0; i < 8; ++i) {
        const char* abh = smem + (size_t)((mykh * 8 + i) * 1024) + lane * 16;
        bf16x8 ahh = *(const bf16x8*)abh;
        bf16x8 ahl = *(const bf16x8*)(abh + 16384);
        f32x4& acc = ((i & 3) == 0) ? acc0 : ((i & 3) == 1) ? acc1 : ((i & 3) == 2) ? acc2 : acc3;
        acc = __builtin_amdgcn_mfma_f32_16x16x32_bf16(ahh, Bh[i], acc, 0, 0, 0);
        acc = __builtin_amdgcn_mfma_f32_16x16x32_bf16(ahh, Bl[i], acc, 0, 0, 0);
        acc = __builtin_amdgcn_mfma_f32_16x16x32_bf16(ahl, Bh[i], acc, 0, 0, 0);
      }
      f32x4 acc = (acc0 + acc1) + (acc2 + acc3);
      const int slot = (myct == 0) ? 0 : 1;
      const int prow = lane & 15;
      const int bcol = (lane >> 4) << 2;
#pragma unroll
      for (int q = 0; q < 4; ++q)
        LP[PREP_F + (mykh * 2 + slot) * 272 + prow * 17 + bcol + q] = acc[q];
    }

    // -------- out-dot (waves 6,7): 256 tasks = 16 b x 16 ks, 2 per thread --------
    if (wv >= 6) {
#pragma unroll
      for (int tk = 0; tk < 2; ++tk) {
        const int task = (tid - 384) + tk * 128;
        const int b = task & 15, ks = task >> 4;
        const float* woc = &LP[WOC_F];
        float oa = 0.f;
#pragma unroll
        for (int c = 0; c < 4; ++c) {
          const uint4 wh = *(const uint4*)(smem + (size_t)(ks * 1024) + (b | (c << 4)) * 16);
          const uint4 wl = *(const uint4*)(smem + (size_t)(16384 + ks * 1024) + (b | (c << 4)) * 16);
          int k0 = ks * 32 + c * 8;
          oa = fmaf(bfhilo(wh.x & 0xFFFFu, wl.x & 0xFFFFu), woc[k0 + 0], oa);
          oa = fmaf(bfhilo(wh.x >> 16, wl.x >> 16), woc[k0 + 1], oa);
          oa = fmaf(bfhilo(wh.y & 0xFFFFu, wl.y & 0xFFFFu), woc[k0 + 2], oa);
          oa = fmaf(bfhilo(wh.y >> 16, wl.y >> 16), woc[k0 + 3], oa);
          oa = fmaf(bfhilo(wh.z & 0xFFFFu, wl.z & 0xFFFFu), woc[k0 + 4], oa);
          oa = fmaf(bfhilo(wh.z >> 16, wl.z >> 16), woc[k0 + 5], oa);
          oa = fmaf(bfhilo(wh.w & 0xFFFFu, wl.w & 0xFFFFu), woc[k0 + 6], oa);
          oa = fmaf(bfhilo(wh.w >> 16, wl.w >> 16), woc[k0 + 7], oa);
        }
        LP[ORED_F + b * 17 + ks] = oa;
      }
    }
    __syncthreads();   // sync B

    if (!last) {
      // -------- gates (tid<128) -> shfl pack -> publish --------
      if (tid < 128) {
        const int b = tid & 15, jj = tid >> 4;
        float pr  = LP[PREP_F + 1 * 272 + jj * 17 + b] + LP[PREP_F + 3 * 272 + jj * 17 + b];
        float pz  = LP[PREP_F + 1 * 272 + (8 + jj) * 17 + b] + LP[PREP_F + 3 * 272 + (8 + jj) * 17 + b];
        float pnh = LP[PREP_F + 0 * 272 + jj * 17 + b] + LP[PREP_F + 2 * 272 + jj * 17 + b]
                  + LP[SB_F + 48 + jj];
        float pni;
        if (teacher) {
          pr += LP[XPRE_F + jj * 17 + b] + LP[SB_F + jj];
          pz += LP[XPRE_F + (8 + jj) * 17 + b] + LP[SB_F + 8 + jj];
          pni = LP[XPRE_F + (16 + jj) * 17 + b] + LP[SB_F + 56 + jj];
        } else {
          float xl = LP[XLAST_F + b];
          pr += LP[SB_F + 16 + jj] + LP[SB_F + 32 + jj] * xl;
          pz += LP[SB_F + 24 + jj] + LP[SB_F + 40 + jj] * xl;
          pni = LP[PREP_F + 0 * 272 + (8 + jj) * 17 + b] + LP[PREP_F + 2 * 272 + (8 + jj) * 17 + b]
              + LP[SB_F + 64 + jj] + LP[SB_F + 72 + jj] * xl;
        }
        size_t hoff = (size_t)(s >> 2) * 1024 + (size_t)(b | ((s & 3) << 4)) * 16 + (size_t)jj * 2;
        float hp = bfhilo(ah16[hoff >> 1], ah16[(hoff + 16384) >> 1]);
        float rg = 1.f / (1.f + expf(-pr));
        float zg = 1.f / (1.f + expf(-pz));
        float ng = tanhf(fmaf(rg, pnh, pni));
        float hv = fmaf(zg, hp - ng, ng);
        float hvp = __shfl_xor(hv, 16, 64);   // partner dim jj^1, same batch
        if ((jj & 1) == 0) {
          unsigned h0h = rne16(hv), h1h = rne16(hvp);
          float r0 = hv  - __uint_as_float(h0h << 16);
          float r1 = hvp - __uint_as_float(h1h << 16);
          unsigned hw = h0h | (h1h << 16);
          unsigned lw = rne16(r0) | (rne16(r1) << 16);
          char* dst = data + (size_t)(hist ? (t + 1) : ((t + 1) & 1)) * STEP_BYTES
                    + (size_t)g * GRP_BYTES;
          unsigned* dhh = (unsigned*)(dst + hoff);
          unsigned* dhl = (unsigned*)(dst + 16384 + hoff);
          if (mode == 2) {
            *(volatile unsigned*)dhh = hw;
            *(volatile unsigned*)dhl = lw;
          } else {
            __hip_atomic_store(dhh, hw, __ATOMIC_RELAXED, __HIP_MEMORY_SCOPE_AGENT);
            __hip_atomic_store(dhl, lw, __ATOMIC_RELAXED, __HIP_MEMORY_SCOPE_AGENT);
          }
        }
      }
      // -------- barrier: drain, arrive, hidden work, poll, release --------
      asm volatile("s_waitcnt vmcnt(0)" ::: "memory");
      __syncthreads();   // sync C: all publishes complete group-visible
      const unsigned tgt = (unsigned)(t + 2);
      if (tid == 0) flag_put(tgt);
      if (t >= 1 && tid >= 256 && tid < 272) {
        const int b = tid - 256;
        float o = LP[SB_F + 80];
#pragma unroll
        for (int i = 0; i < 16; ++i) o += LP[ORED_F + b * 17 + i];
        out[((size_t)(bg0 + b) * 512 + (t - 1)) * 64 + s] = o;
      }
      stage_x(t + 1);   // hidden under the detect window (waves 0-5)
      if (wv == 7) flag_poll(tgt);
      __syncthreads();   // sync D: release
    } else {
      // t == 512: ORED holds h_arr[511] partials
      if (tid >= 256 && tid < 272) {
        const int b = tid - 256;
        float o = LP[SB_F + 80];
#pragma unroll
        for (int i = 0; i < 16; ++i) o += LP[ORED_F + b * 17 + i];
        out[((size_t)(bg0 + b) * 512 + 511) * 64 + s] = o;
      }
    }
  }
}

extern "C" void kernel_launch(void* const* d_in, const int* in_sizes, int n_in,
                              void* d_out, int out_size, void* d_ws, size_t ws_size,
                              hipStream_t stream) {
  (void)in_sizes; (void)n_in; (void)out_size;
  const float* x    = (const float*)d_in[0];
  const float* tp   = (const float*)d_in[1];
  const int*   mask = (const int*)d_in[2];
  const float* W_ih = (const float*)d_in[3];
  const float* W_hh = (const float*)d_in[4];
  const float* b_ih = (const float*)d_in[5];
  const float* b_hh = (const float*)d_in[6];
  const float* W_out= (const float*)d_in[7];
  const float* b_out= (const float*)d_in[8];
  float* out = (float*)d_out;
  if (ws_size < FB_NEEDED) return;
  int hist = (ws_size >= HIST_NEEDED) ? 1 : 0;
  hipMemsetAsync(d_ws, 0, 4096, stream);
  hipFuncSetAttribute((const void*)gru_persistent,
                      hipFuncAttributeMaxDynamicSharedMemorySize, LDS_BYTES);
  hipLaunchKernelGGL(gru_persistent, dim3(NWG), dim3(TB), LDS_BYTES, stream,
                     x, tp, mask, W_ih, W_hh, b_ih, b_hh, W_out, b_out,
                     (char*)d_ws, out, hist);
}

// Round 10
// 4380.286 us; speedup vs baseline: 1.4312x; 1.4312x over previous
//
#include <hip/hip_runtime.h>
#include <math.h>

// B=128, T=512, D=64, H=512. 512 WGs = 64 dim-slices x 8 batch-groups (16 batches each).
// Gates via split-bf16 MFMA (3-term), weight B-frags in registers (6 MFMA waves: 3ct x 2 K-half).
// h exchange modes:
//   mode 2 (XCD-local + hist): group == physical XCD (HW_REG_XCC_ID + atomic rank; verified
//     round-robin rounds 7/8). h publish = plain stores (L1 write-through -> local L2); h fetch =
//     plain cached loads. Barrier = ROUND-8-PROVEN per-WG flag words + 64-lane RMW poll
//     (fetch_add(+0x10000), low16 = arrivals; non-idempotent => cannot be demoted to cached load),
//     arrival = fetch_add(+1) on own word. ROUND-10 CHANGE: each flag word strided to its OWN
//     128B cache line -> poll sweep is 64 parallel lines instead of 4096 serialized RMWs on 2
//     lines (round-8's 10us/step cost). Poll backoff s_sleep(4).
//   mode 1 (agent + hist): round-5/6 proven path — sc1 flag stores, 64-lane sc1 polls, plain loads.
//   mode 0 (agent + ring): round-4 proven path — sc1 everything, 2-buffer ring.
#define TB 512
#define NWG 512

typedef __attribute__((ext_vector_type(8))) short bf16x8;
typedef __attribute__((ext_vector_type(4))) float f32x4;
typedef unsigned long long u64;

// LDS float offsets. Bytes [0,32768) = A-frags (h staged, frag-linear; also B-build scratch at init).
#define PREP_F 8192      // [2kh][2slot][16 rows][17] = 1088 f32
#define XPRE_F 9280      // 24 x 17 (teacher x-dot r8,z8,n8)
#define ORED_F 9688      // 16 x 17 (out partials)
#define WOC_F  9960      // 512 (W_out column s)
#define WIH_F  10472     // 24 x 66 (W_ih slice rows)
#define SB_F   12056     // 96 biases ([80]=b_out[s])
#define XLAST_F 12152    // 16 (x last channel, AR)
#define MSK_F  12168     // 512 ints
#define ROLE_F 12680     // 4 ints (g, slice, localmode)
#define LDS_FLOATS 12688
#define LDS_BYTES (LDS_FLOATS * 4)   // 50752

#define FLAG_STRIDE 32               // words: one flag per 128B line
#define FLAGS_BYTES (512 * 128)      // 64KB: 8 groups x 64 WGs, one line each
#define REG_OFF FLAGS_BYTES          // registration counters
#define CTRL_BYTES (FLAGS_BYTES + 4096)
#define GRP_BYTES 32768
#define STEP_BYTES (8 * GRP_BYTES)   // 256KB per step (8 groups)
#define DATA_OFF CTRL_BYTES
#define HIST_NEEDED ((unsigned long long)DATA_OFF + 513ull * STEP_BYTES)
#define FB_NEEDED   ((unsigned long long)DATA_OFF + 2ull * STEP_BYTES)

__device__ __forceinline__ unsigned rne16(float f) {
  unsigned u = __float_as_uint(f);
  return (u + 0x7FFFu + ((u >> 16) & 1u)) >> 16;
}
__device__ __forceinline__ float bfhilo(unsigned hh, unsigned hl) {
  return __uint_as_float(hh << 16) + __uint_as_float(hl << 16);
}

__global__ __launch_bounds__(TB, 4) void gru_persistent(
    const float* __restrict__ x, const float* __restrict__ tp, const int* __restrict__ mask,
    const float* __restrict__ W_ih, const float* __restrict__ W_hh,
    const float* __restrict__ b_ih, const float* __restrict__ b_hh,
    const float* __restrict__ W_out, const float* __restrict__ b_out,
    char* __restrict__ ws, float* __restrict__ out, int hist)
{
  extern __shared__ char smem[];
  float* LP = (float*)smem;
  int* MSK = (int*)&LP[MSK_F];
  volatile int* ROLE = (volatile int*)&LP[ROLE_F];
  const int tid = threadIdx.x;
  const int lane = tid & 63;
  const int wv   = tid >> 6;
  const int myct = wv >> 1, mykh = wv & 1;

  unsigned* flags = (unsigned*)ws;                 // strided: flags[((g<<6)+s)*FLAG_STRIDE]
  unsigned* reg   = (unsigned*)(ws + REG_OFF);     // reg[0..7]=per-XCD count, reg[8]=total
  char* data = ws + DATA_OFF;

  // ---------------- registration: discover XCD placement ----------------
  if (tid == 0) {
    unsigned xcc = 0;
    asm volatile("s_getreg_b32 %0, hwreg(HW_REG_XCC_ID)" : "=s"(xcc));
    xcc &= 7u;
    unsigned rank = __hip_atomic_fetch_add(&reg[xcc], 1u, __ATOMIC_RELAXED, __HIP_MEMORY_SCOPE_AGENT);
    __hip_atomic_fetch_add(&reg[8], 1u, __ATOMIC_RELAXED, __HIP_MEMORY_SCOPE_AGENT);
    int cnt = 0;
    while (__hip_atomic_load(&reg[8], __ATOMIC_RELAXED, __HIP_MEMORY_SCOPE_AGENT) < (unsigned)NWG) {
      __builtin_amdgcn_s_sleep(8);
      if (++cnt > 2000000) break;   // escape hatch
    }
    int ok = 1;
    for (int i = 0; i < 8; ++i)
      ok &= (__hip_atomic_load(&reg[i], __ATOMIC_RELAXED, __HIP_MEMORY_SCOPE_AGENT) == 64u);
    ok &= (rank < 64u);
    ROLE[0] = ok ? (int)xcc : (int)(blockIdx.x & 7);
    ROLE[1] = ok ? (int)rank : (int)(blockIdx.x >> 3);
    ROLE[2] = ok;
  }
  __syncthreads();
  const int g = ROLE[0];
  const int s = ROLE[1];
  const int mode = (ROLE[2] && hist) ? 2 : (hist ? 1 : 0);
  const int bg0 = g * 16;
  const int j0  = 8 * s;

  // ---------------- init staging ----------------
  MSK[tid] = mask[tid];
  if (tid < 65) {
    for (int p = 0; p < 24; ++p) {
      int row = (p < 8) ? (j0 + p) : (p < 16) ? (512 + j0 + (p - 8)) : (1024 + j0 + (p - 16));
      LP[WIH_F + p * 66 + tid] = W_ih[(size_t)row * 65 + tid];
    }
  }
  LP[WOC_F + tid] = W_out[(size_t)tid * 64 + s];
  if (tid < 16) {
    int row = (tid < 8) ? (j0 + tid) : (512 + j0 + (tid - 8));
    const float* wi = W_ih + (size_t)row * 65;
    float bt = b_ih[row] + b_hh[row];
    float bp = 0.f;
    for (int d = 0; d < 64; ++d) bp = fmaf(wi[d], b_out[d], bp);
    LP[SB_F + tid]      = bt;        // teacher rz bias
    LP[SB_F + 16 + tid] = bt + bp;   // AR rz bias
    LP[SB_F + 32 + tid] = wi[64];    // xlast coef rz
  } else if (tid < 24) {
    int jj = tid - 16;
    int row = 1024 + j0 + jj;
    const float* wi = W_ih + (size_t)row * 65;
    float bp = 0.f;
    for (int d = 0; d < 64; ++d) bp = fmaf(wi[d], b_out[d], bp);
    LP[SB_F + 48 + jj] = b_hh[row];
    LP[SB_F + 56 + jj] = b_ih[row];
    LP[SB_F + 64 + jj] = b_ih[row] + bp;
    LP[SB_F + 72 + jj] = wi[64];
  }
  if (tid == 0) LP[SB_F + 80] = b_out[s];
  __syncthreads();

  // ---------------- build B-frags to registers, 3 passes via A-region scratch ----------------
  bf16x8 Bh[8], Bl[8];
  {
    unsigned short* bw16 = (unsigned short*)smem;
    for (int ct = 0; ct < 3; ++ct) {
      const int k = tid;
      const float* wo = W_out + (size_t)k * 64;
      for (int wr = 0; wr < 16; ++wr) {
        float w;
        if (ct == 1) {
          int row = (wr < 8) ? (j0 + wr) : (512 + j0 + wr - 8);
          w = W_hh[(size_t)row * 512 + k];
        } else if (ct == 0) {
          if (wr < 8) w = W_hh[(size_t)(1024 + j0 + wr) * 512 + k];
          else {
            const float* wrp = &LP[WIH_F + (16 + wr - 8) * 66];
            float a = 0.f;
#pragma unroll 8
            for (int d = 0; d < 64; ++d) a = fmaf(wrp[d], wo[d], a);
            w = a;
          }
        } else {
          int row = (wr < 8) ? (j0 + wr) : (512 + j0 + wr - 8);
          const float* wrp = &LP[WIH_F + wr * 66];
          float a = 0.f;
#pragma unroll 8
          for (int d = 0; d < 64; ++d) a = fmaf(wrp[d], wo[d], a);
          w = a + W_hh[(size_t)row * 512 + k];
        }
        unsigned wh = rne16(w);
        float resid = w - __uint_as_float(wh << 16);
        unsigned wl = rne16(resid);
        int base = (k >> 5) * 1024 + (wr | (((k >> 3) & 3) << 4)) * 16 + (k & 7) * 2;
        bw16[base >> 1] = (unsigned short)wh;
        bw16[(base + 16384) >> 1] = (unsigned short)wl;
      }
      __syncthreads();
      if (wv < 6 && myct == ct) {
#pragma unroll
        for (int i = 0; i < 8; ++i) {
          Bh[i] = *(const bf16x8*)(smem + (mykh * 8 + i) * 1024 + lane * 16);
          Bl[i] = *(const bf16x8*)(smem + 16384 + (mykh * 8 + i) * 1024 + lane * 16);
        }
      }
      __syncthreads();
    }
  }

  // ---------------- zero h0 (buffer 0) ----------------
  if (tid < 32) {
    const int b = tid & 15, term = tid >> 4;
    size_t off = (size_t)(term * 16 + (s >> 2)) * 1024 + (size_t)(b | ((s & 3) << 4)) * 16;
    u64* p = (u64*)(data + (size_t)g * GRP_BYTES + off);
    if (mode == 2) {
      *(volatile u64*)p = 0ull; *(volatile u64*)(p + 1) = 0ull;
    } else {
      __hip_atomic_store(p,     0ull, __ATOMIC_RELAXED, __HIP_MEMORY_SCOPE_AGENT);
      __hip_atomic_store(p + 1, 0ull, __ATOMIC_RELAXED, __HIP_MEMORY_SCOPE_AGENT);
    }
  }

  // teacher x-dot staging for step tt (h-independent; runs in barrier windows)
  auto stage_x = [&](int tt) {
    if (tt >= 512) return;
    if (MSK[tt] != 0) {
      if (tid < 384) {
        const int xr = tid >> 4, b = tid & 15;
        const float* wrow = &LP[WIH_F + xr * 66];
        size_t ti = (size_t)(bg0 + b) * 512 + tt;
        float del = tp[ti] - (tt > 0 ? tp[ti - 1] : 0.f);
        float xa = wrow[64] * del;
        const float4* x4 = (const float4*)(x + ti * 64);
#pragma unroll
        for (int d4 = 0; d4 < 16; ++d4) {
          float4 xv = x4[d4];
          xa = fmaf(wrow[d4 * 4 + 0], xv.x, xa);
          xa = fmaf(wrow[d4 * 4 + 1], xv.y, xa);
          xa = fmaf(wrow[d4 * 4 + 2], xv.z, xa);
          xa = fmaf(wrow[d4 * 4 + 3], xv.w, xa);
        }
        LP[XPRE_F + xr * 17 + b] = xa;
      }
    } else if (tid < 16) {
      LP[XLAST_F + tid] = x[((size_t)(bg0 + tid) * 512 + tt) * 64 + 63];
    }
  };

  // Flag word for (group, wg-index i): own 128B line.
  auto flag_addr = [&](int i) -> unsigned* { return &flags[(size_t)((g << 6) + i) * FLAG_STRIDE]; };
  // Arrival: mode2 = +1 RMW at LOCAL L2 (low16 = this WG's epoch count); else sc1 store to LLC.
  auto flag_put = [&](unsigned tgt_epoch) {
    if (mode == 2)
      __hip_atomic_fetch_add(flag_addr(s), 1u, __ATOMIC_RELAXED, __HIP_MEMORY_SCOPE_WORKGROUP);
    else
      __hip_atomic_store(flag_addr(s), tgt_epoch, __ATOMIC_RELAXED, __HIP_MEMORY_SCOPE_AGENT);
  };
  // Wait (round-8-proven 64-lane form): RMW poll of all 64 per-WG words; each word on its own line.
  auto flag_poll = [&](unsigned tgt_epoch) {
    int cnt = 0;
    while (true) {
      unsigned v;
      if (mode == 2)
        v = __hip_atomic_fetch_add(flag_addr(lane), 0x10000u, __ATOMIC_RELAXED,
                                   __HIP_MEMORY_SCOPE_WORKGROUP) & 0xFFFFu;
      else
        v = __hip_atomic_load(flag_addr(lane), __ATOMIC_RELAXED, __HIP_MEMORY_SCOPE_AGENT);
      if (__ballot(v < tgt_epoch) == 0ull) break;
      __builtin_amdgcn_s_sleep(4);
      if (++cnt > 300000) break;   // escape hatch: wrong answer instead of hang
    }
  };

  stage_x(0);
  // initial barrier: h0 zeros + stage_x(0) done group-wide
  asm volatile("s_waitcnt vmcnt(0)" ::: "memory");
  __syncthreads();
  if (tid == 0) flag_put(1u);
  if (wv == 7) flag_poll(1u);
  __syncthreads();

  const unsigned short* ah16 = (const unsigned short*)smem;

  for (int t = 0; t <= 512; ++t) {
    const bool last = (t == 512);
    const bool teacher = (!last) && (MSK[t] != 0);
    const int csel = teacher ? 1 : 2;
    const char* src = data + (size_t)(hist ? t : (t & 1)) * STEP_BYTES + (size_t)g * GRP_BYTES;

    // -------- phase A: fetch 32KB h(t) image into LDS (frag-linear identity copy) --------
    if (mode == 0) {
      u64 a0[4], a1[4];
#pragma unroll
      for (int i = 0; i < 4; ++i) {
        const u64* p = (const u64*)(src + (size_t)(i * 512 + tid) * 16);
        a0[i] = __hip_atomic_load(p,     __ATOMIC_RELAXED, __HIP_MEMORY_SCOPE_AGENT);
        a1[i] = __hip_atomic_load(p + 1, __ATOMIC_RELAXED, __HIP_MEMORY_SCOPE_AGENT);
      }
#pragma unroll
      for (int i = 0; i < 4; ++i) {
        u64* d = (u64*)(smem + (size_t)(i * 512 + tid) * 16);
        d[0] = a0[i]; d[1] = a1[i];
      }
    } else {
      uint4 v[4];
#pragma unroll
      for (int i = 0; i < 4; ++i) v[i] = *(const uint4*)(src + (size_t)(i * 512 + tid) * 16);
#pragma unroll
      for (int i = 0; i < 4; ++i) *(uint4*)(smem + (size_t)(i * 512 + tid) * 16) = v[i];
    }
    __syncthreads();   // sync A

    // -------- MFMA (waves 0-5): ct0 always, ct1 teacher, ct2 AR; K-half = mykh --------
    if (!last && wv < 6 && (myct == 0 || myct == csel)) {
      f32x4 acc0 = {0.f, 0.f, 0.f, 0.f};
      f32x4 acc1 = {0.f, 0.f, 0.f, 0.f};
      f32x4 acc2 = {0.f, 0.f, 0.f, 0.f};
      f32x4 acc3 = {0.f, 0.f, 0.f, 0.f};
#pragma unroll
      for (int i = 0; i < 8; ++i) {
        const char* abh = smem + (size_t)((mykh * 8 + i) * 1024) + lane * 16;
        bf16x8 ahh = *(const bf16x8*)abh;
        bf16x8 ahl = *(const bf16x8*)(abh + 16384);
        f32x4& acc = ((i & 3) == 0) ? acc0 : ((i & 3) == 1) ? acc1 : ((i & 3) == 2) ? acc2 : acc3;
        acc = __builtin_amdgcn_mfma_f32_16x16x32_bf16(ahh, Bh[i], acc, 0, 0, 0);
        acc = __builtin_amdgcn_mfma_f32_16x16x32_bf16(ahh, Bl[i], acc, 0, 0, 0);
        acc = __builtin_amdgcn_mfma_f32_16x16x32_bf16(ahl, Bh[i], acc, 0, 0, 0);
      }
      f32x4 acc = (acc0 + acc1) + (acc2 + acc3);
      const int slot = (myct == 0) ? 0 : 1;
      const int prow = lane & 15;
      const int bcol = (lane >> 4) << 2;
#pragma unroll
      for (int q = 0; q < 4; ++q)
        LP[PREP_F + (mykh * 2 + slot) * 272 + prow * 17 + bcol + q] = acc[q];
    }

    // -------- out-dot (waves 6,7): 256 tasks = 16 b x 16 ks, 2 per thread --------
    if (wv >= 6) {
#pragma unroll
      for (int tk = 0; tk < 2; ++tk) {
        const int task = (tid - 384) + tk * 128;
        const int b = task & 15, ks = task >> 4;
        const float* woc = &LP[WOC_F];
        float oa = 0.f;
#pragma unroll
        for (int c = 0; c < 4; ++c) {
          const uint4 wh = *(const uint4*)(smem + (size_t)(ks * 1024) + (b | (c << 4)) * 16);
          const uint4 wl = *(const uint4*)(smem + (size_t)(16384 + ks * 1024) + (b | (c << 4)) * 16);
          int k0 = ks * 32 + c * 8;
          oa = fmaf(bfhilo(wh.x & 0xFFFFu, wl.x & 0xFFFFu), woc[k0 + 0], oa);
          oa = fmaf(bfhilo(wh.x >> 16, wl.x >> 16), woc[k0 + 1], oa);
          oa = fmaf(bfhilo(wh.y & 0xFFFFu, wl.y & 0xFFFFu), woc[k0 + 2], oa);
          oa = fmaf(bfhilo(wh.y >> 16, wl.y >> 16), woc[k0 + 3], oa);
          oa = fmaf(bfhilo(wh.z & 0xFFFFu, wl.z & 0xFFFFu), woc[k0 + 4], oa);
          oa = fmaf(bfhilo(wh.z >> 16, wl.z >> 16), woc[k0 + 5], oa);
          oa = fmaf(bfhilo(wh.w & 0xFFFFu, wl.w & 0xFFFFu), woc[k0 + 6], oa);
          oa = fmaf(bfhilo(wh.w >> 16, wl.w >> 16), woc[k0 + 7], oa);
        }
        LP[ORED_F + b * 17 + ks] = oa;
      }
    }
    __syncthreads();   // sync B

    if (!last) {
      // -------- gates (tid<128) -> shfl pack -> publish --------
      if (tid < 128) {
        const int b = tid & 15, jj = tid >> 4;
        float pr  = LP[PREP_F + 1 * 272 + jj * 17 + b] + LP[PREP_F + 3 * 272 + jj * 17 + b];
        float pz  = LP[PREP_F + 1 * 272 + (8 + jj) * 17 + b] + LP[PREP_F + 3 * 272 + (8 + jj) * 17 + b];
        float pnh = LP[PREP_F + 0 * 272 + jj * 17 + b] + LP[PREP_F + 2 * 272 + jj * 17 + b]
                  + LP[SB_F + 48 + jj];
        float pni;
        if (teacher) {
          pr += LP[XPRE_F + jj * 17 + b] + LP[SB_F + jj];
          pz += LP[XPRE_F + (8 + jj) * 17 + b] + LP[SB_F + 8 + jj];
          pni = LP[XPRE_F + (16 + jj) * 17 + b] + LP[SB_F + 56 + jj];
        } else {
          float xl = LP[XLAST_F + b];
          pr += LP[SB_F + 16 + jj] + LP[SB_F + 32 + jj] * xl;
          pz += LP[SB_F + 24 + jj] + LP[SB_F + 40 + jj] * xl;
          pni = LP[PREP_F + 0 * 272 + (8 + jj) * 17 + b] + LP[PREP_F + 2 * 272 + (8 + jj) * 17 + b]
              + LP[SB_F + 64 + jj] + LP[SB_F + 72 + jj] * xl;
        }
        size_t hoff = (size_t)(s >> 2) * 1024 + (size_t)(b | ((s & 3) << 4)) * 16 + (size_t)jj * 2;
        float hp = bfhilo(ah16[hoff >> 1], ah16[(hoff + 16384) >> 1]);
        float rg = 1.f / (1.f + expf(-pr));
        float zg = 1.f / (1.f + expf(-pz));
        float ng = tanhf(fmaf(rg, pnh, pni));
        float hv = fmaf(zg, hp - ng, ng);
        float hvp = __shfl_xor(hv, 16, 64);   // partner dim jj^1, same batch
        if ((jj & 1) == 0) {
          unsigned h0h = rne16(hv), h1h = rne16(hvp);
          float r0 = hv  - __uint_as_float(h0h << 16);
          float r1 = hvp - __uint_as_float(h1h << 16);
          unsigned hw = h0h | (h1h << 16);
          unsigned lw = rne16(r0) | (rne16(r1) << 16);
          char* dst = data + (size_t)(hist ? (t + 1) : ((t + 1) & 1)) * STEP_BYTES
                    + (size_t)g * GRP_BYTES;
          unsigned* dhh = (unsigned*)(dst + hoff);
          unsigned* dhl = (unsigned*)(dst + 16384 + hoff);
          if (mode == 2) {
            *(volatile unsigned*)dhh = hw;
            *(volatile unsigned*)dhl = lw;
          } else {
            __hip_atomic_store(dhh, hw, __ATOMIC_RELAXED, __HIP_MEMORY_SCOPE_AGENT);
            __hip_atomic_store(dhl, lw, __ATOMIC_RELAXED, __HIP_MEMORY_SCOPE_AGENT);
          }
        }
      }
      // -------- barrier: drain, arrive, hidden work, poll, release --------
      asm volatile("s_waitcnt vmcnt(0)" ::: "memory");
      __syncthreads();   // sync C: all publishes complete group-visible
      const unsigned tgt = (unsigned)(t + 2);
      if (tid == 0) flag_put(tgt);
      if (t >= 1 && tid >= 256 && tid < 272) {
        const int b = tid - 256;
        float o = LP[SB_F + 80];
#pragma unroll
        for (int i = 0; i < 16; ++i) o += LP[ORED_F + b * 17 + i];
        out[((size_t)(bg0 + b) * 512 + (t - 1)) * 64 + s] = o;
      }
      stage_x(t + 1);   // hidden under the poll window (waves 0-5)
      if (wv == 7) flag_poll(tgt);
      __syncthreads();   // sync D: release
    } else {
      // t == 512: ORED holds h_arr[511] partials
      if (tid >= 256 && tid < 272) {
        const int b = tid - 256;
        float o = LP[SB_F + 80];
#pragma unroll
        for (int i = 0; i < 16; ++i) o += LP[ORED_F + b * 17 + i];
        out[((size_t)(bg0 + b) * 512 + 511) * 64 + s] = o;
      }
    }
  }
}

extern "C" void kernel_launch(void* const* d_in, const int* in_sizes, int n_in,
                              void* d_out, int out_size, void* d_ws, size_t ws_size,
                              hipStream_t stream) {
  (void)in_sizes; (void)n_in; (void)out_size;
  const float* x    = (const float*)d_in[0];
  const float* tp   = (const float*)d_in[1];
  const int*   mask = (const int*)d_in[2];
  const float* W_ih = (const float*)d_in[3];
  const float* W_hh = (const float*)d_in[4];
  const float* b_ih = (const float*)d_in[5];
  const float* b_hh = (const float*)d_in[6];
  const float* W_out= (const float*)d_in[7];
  const float* b_out= (const float*)d_in[8];
  float* out = (float*)d_out;
  if (ws_size < FB_NEEDED) return;
  int hist = (ws_size >= HIST_NEEDED) ? 1 : 0;
  hipMemsetAsync(d_ws, 0, CTRL_BYTES, stream);
  hipFuncSetAttribute((const void*)gru_persistent,
                      hipFuncAttributeMaxDynamicSharedMemorySize, LDS_BYTES);
  hipLaunchKernelGGL(gru_persistent, dim3(NWG), dim3(TB), LDS_BYTES, stream,
                     x, tp, mask, W_ih, W_hh, b_ih, b_hh, W_out, b_out,
                     (char*)d_ws, out, hist);
}

// Round 11
// 3597.798 us; speedup vs baseline: 1.7424x; 1.2175x over previous
//
#include <hip/hip_runtime.h>
#include <math.h>

// B=128, T=512, D=64, H=512. 256 WGs = 32 dim-slices (16 dims each) x 8 XCD-groups (16 batches).
// 1 WG/CU. Gates via split-bf16 MFMA (3-term), weight B-frags in registers (6 MFMA waves:
// 3ct x 2 K-half, each holding 2 col-tiles = 128 VGPR).
// Modes: 2 = XCD-local hist (plain-store publish -> local L2; plain-load fetch of write-once
// buffers; flags = per-WG strided lines, arrival fetch_add(+1), poll fetch_add(+0x10000) RMW
// with PER-LANE EXIT); 1 = agent/LLC hist; 0 = agent ring.
#define TB 512
#define NWG 256
#define NSL 32

typedef __attribute__((ext_vector_type(8))) short bf16x8;
typedef __attribute__((ext_vector_type(4))) float f32x4;
typedef unsigned long long u64;

// LDS float offsets. Bytes [0,32768) = A-frags (h image; B-build scratch at init).
#define PREP_F 8192      // [2kh][2slot][32 rows][17] = 2176
#define XPRE_F 10368     // 48 x 17 = 816 (teacher x-dot r16,z16,n16)
#define ORED_F 11184     // 2 x 16 x 17 = 544 (out partials, 2 dims)
#define WOC_F  11728     // 2 x 512 (W_out cols 2s, 2s+1)
#define WIH_F  12752     // 48 x 66 = 3168
#define SB_F   15920     // 176 biases ([160..161]=b_out)
#define XLAST_F 16096    // 16
#define MSK_F  16112     // 512 ints
#define ROLE_F 16624     // 4 ints
#define LDS_FLOATS 16640
#define LDS_BYTES (LDS_FLOATS * 4)   // 66560

#define FLAG_STRIDE 32               // one flag word per 128B line
#define FLAGS_BYTES (NWG * 128)      // 32KB
#define REG_OFF FLAGS_BYTES
#define CTRL_BYTES (FLAGS_BYTES + 4096)
#define GRP_BYTES 32768
#define STEP_BYTES (8 * GRP_BYTES)
#define DATA_OFF CTRL_BYTES
#define HIST_NEEDED ((unsigned long long)DATA_OFF + 513ull * STEP_BYTES)
#define FB_NEEDED   ((unsigned long long)DATA_OFF + 2ull * STEP_BYTES)

__device__ __forceinline__ unsigned rne16(float f) {
  unsigned u = __float_as_uint(f);
  return (u + 0x7FFFu + ((u >> 16) & 1u)) >> 16;
}
__device__ __forceinline__ float bfhilo(unsigned hh, unsigned hl) {
  return __uint_as_float(hh << 16) + __uint_as_float(hl << 16);
}

__global__ __launch_bounds__(TB, 2) void gru_persistent(
    const float* __restrict__ x, const float* __restrict__ tp, const int* __restrict__ mask,
    const float* __restrict__ W_ih, const float* __restrict__ W_hh,
    const float* __restrict__ b_ih, const float* __restrict__ b_hh,
    const float* __restrict__ W_out, const float* __restrict__ b_out,
    char* __restrict__ ws, float* __restrict__ out, int hist)
{
  extern __shared__ char smem[];
  float* LP = (float*)smem;
  int* MSK = (int*)&LP[MSK_F];
  volatile int* ROLE = (volatile int*)&LP[ROLE_F];
  const int tid = threadIdx.x;
  const int lane = tid & 63;
  const int wv   = tid >> 6;
  const int myct = wv >> 1, mykh = wv & 1;

  unsigned* flags = (unsigned*)ws;
  unsigned* reg   = (unsigned*)(ws + REG_OFF);
  char* data = ws + DATA_OFF;

  // ---------------- registration: discover XCD placement ----------------
  if (tid == 0) {
    unsigned xcc = 0;
    asm volatile("s_getreg_b32 %0, hwreg(HW_REG_XCC_ID)" : "=s"(xcc));
    xcc &= 7u;
    unsigned rank = __hip_atomic_fetch_add(&reg[xcc], 1u, __ATOMIC_RELAXED, __HIP_MEMORY_SCOPE_AGENT);
    __hip_atomic_fetch_add(&reg[8], 1u, __ATOMIC_RELAXED, __HIP_MEMORY_SCOPE_AGENT);
    int cnt = 0;
    while (__hip_atomic_load(&reg[8], __ATOMIC_RELAXED, __HIP_MEMORY_SCOPE_AGENT) < (unsigned)NWG) {
      __builtin_amdgcn_s_sleep(8);
      if (++cnt > 2000000) break;
    }
    int ok = 1;
    for (int i = 0; i < 8; ++i)
      ok &= (__hip_atomic_load(&reg[i], __ATOMIC_RELAXED, __HIP_MEMORY_SCOPE_AGENT) == (unsigned)NSL);
    ok &= (rank < (unsigned)NSL);
    ROLE[0] = ok ? (int)xcc : (int)(blockIdx.x & 7);
    ROLE[1] = ok ? (int)rank : (int)(blockIdx.x >> 3);
    ROLE[2] = ok;
  }
  __syncthreads();
  const int g = ROLE[0];
  const int s = ROLE[1];          // 0..31
  const int mode = (ROLE[2] && hist) ? 2 : (hist ? 1 : 0);
  const int bg0 = g * 16;
  const int j0  = 16 * s;
  const int ks0 = s >> 1;
  const int c0  = (2 * s) & 3, c1 = (2 * s + 1) & 3;

  // ---------------- init staging ----------------
  MSK[tid] = mask[tid];
  if (tid < 65) {
    for (int p = 0; p < 48; ++p) {
      int row = (p < 16) ? (j0 + p) : (p < 32) ? (512 + j0 + (p - 16)) : (1024 + j0 + (p - 32));
      LP[WIH_F + p * 66 + tid] = W_ih[(size_t)row * 65 + tid];
    }
  }
  LP[WOC_F + tid]       = W_out[(size_t)tid * 64 + 2 * s];
  LP[WOC_F + 512 + tid] = W_out[(size_t)tid * 64 + 2 * s + 1];
  if (tid < 48) {
    int row = (tid < 16) ? (j0 + tid) : (tid < 32) ? (512 + j0 + (tid - 16)) : (1024 + j0 + (tid - 32));
    const float* wi = W_ih + (size_t)row * 65;
    float bp = 0.f;
    for (int d = 0; d < 64; ++d) bp = fmaf(wi[d], b_out[d], bp);
    if (tid < 32) {
      float bt = b_ih[row] + b_hh[row];
      LP[SB_F + tid]      = bt;        // teacher rz bias
      LP[SB_F + 32 + tid] = bt + bp;   // AR rz bias
      LP[SB_F + 64 + tid] = wi[64];    // xlast coef rz
    } else {
      int jj = tid - 32;
      LP[SB_F + 96 + jj]  = b_hh[row];       // nh bias
      LP[SB_F + 112 + jj] = b_ih[row];       // ni teacher
      LP[SB_F + 128 + jj] = b_ih[row] + bp;  // ni AR
      LP[SB_F + 144 + jj] = wi[64];          // xlast coef n
    }
  } else if (tid < 50) {
    LP[SB_F + 160 + (tid - 48)] = b_out[2 * s + (tid - 48)];
  }
  __syncthreads();

  // ---------------- build B-frags to registers: 3 ct x 2 col-halves via 32KB scratch ----------
  bf16x8 Bh[16], Bl[16];
  {
    unsigned short* bw16 = (unsigned short*)smem;
#pragma unroll
    for (int ct = 0; ct < 3; ++ct) {
#pragma unroll
      for (int hc = 0; hc < 2; ++hc) {
        const int k = tid;
        const float* wo = W_out + (size_t)k * 64;
        for (int c16 = 0; c16 < 16; ++c16) {
          const int col = hc * 16 + c16;
          float w;
          if (ct == 0) {
            if (col < 16) w = W_hh[(size_t)(1024 + j0 + col) * 512 + k];   // nh
            else {                                                          // ni: Wc only
              const float* wrp = &LP[WIH_F + (32 + col - 16) * 66];
              float a = 0.f;
#pragma unroll 8
              for (int d = 0; d < 64; ++d) a = fmaf(wrp[d], wo[d], a);
              w = a;
            }
          } else if (ct == 1) {
            int row = (col < 16) ? (j0 + col) : (512 + j0 + col - 16);
            w = W_hh[(size_t)row * 512 + k];
          } else {
            int row = (col < 16) ? (j0 + col) : (512 + j0 + col - 16);
            const float* wrp = &LP[WIH_F + col * 66];   // r rows 0-15, z rows 16-31
            float a = 0.f;
#pragma unroll 8
            for (int d = 0; d < 64; ++d) a = fmaf(wrp[d], wo[d], a);
            w = a + W_hh[(size_t)row * 512 + k];
          }
          unsigned wh_ = rne16(w);
          float resid = w - __uint_as_float(wh_ << 16);
          unsigned wl_ = rne16(resid);
          int base = (k >> 5) * 1024 + (c16 | (((k >> 3) & 3) << 4)) * 16 + (k & 7) * 2;
          bw16[base >> 1] = (unsigned short)wh_;
          bw16[(base + 16384) >> 1] = (unsigned short)wl_;
        }
        __syncthreads();
        if (wv < 6 && myct == ct) {
#pragma unroll
          for (int i = 0; i < 8; ++i) {
            Bh[hc * 8 + i] = *(const bf16x8*)(smem + (mykh * 8 + i) * 1024 + lane * 16);
            Bl[hc * 8 + i] = *(const bf16x8*)(smem + 16384 + (mykh * 8 + i) * 1024 + lane * 16);
          }
        }
        __syncthreads();
      }
    }
  }

  // ---------------- zero h0 (buffer 0): this WG's 1KB publish region ----------------
  if (tid < 32) {
    const int b = tid & 15, term = tid >> 4;
    char* dst = data + (size_t)g * GRP_BYTES + (size_t)(term * 16 + ks0) * 1024;
    u64* p0 = (u64*)(dst + (size_t)(b | (c0 << 4)) * 16);
    u64* p1 = (u64*)(dst + (size_t)(b | (c1 << 4)) * 16);
    if (mode == 2) {
      *(volatile u64*)p0 = 0ull; *(volatile u64*)(p0 + 1) = 0ull;
      *(volatile u64*)p1 = 0ull; *(volatile u64*)(p1 + 1) = 0ull;
    } else {
      __hip_atomic_store(p0,     0ull, __ATOMIC_RELAXED, __HIP_MEMORY_SCOPE_AGENT);
      __hip_atomic_store(p0 + 1, 0ull, __ATOMIC_RELAXED, __HIP_MEMORY_SCOPE_AGENT);
      __hip_atomic_store(p1,     0ull, __ATOMIC_RELAXED, __HIP_MEMORY_SCOPE_AGENT);
      __hip_atomic_store(p1 + 1, 0ull, __ATOMIC_RELAXED, __HIP_MEMORY_SCOPE_AGENT);
    }
  }

  // teacher x-dot staging for step tt (h-independent; runs in barrier windows)
  auto stage_x = [&](int tt) {
    if (tt >= 512) return;
    if (MSK[tt] != 0) {
      for (int task = tid; task < 768; task += TB) {
        const int xr = task >> 4, b = task & 15;
        const float* wrow = &LP[WIH_F + xr * 66];
        size_t ti = (size_t)(bg0 + b) * 512 + tt;
        float del = tp[ti] - (tt > 0 ? tp[ti - 1] : 0.f);
        float xa = wrow[64] * del;
        const float4* x4 = (const float4*)(x + ti * 64);
#pragma unroll
        for (int d4 = 0; d4 < 16; ++d4) {
          float4 xv = x4[d4];
          xa = fmaf(wrow[d4 * 4 + 0], xv.x, xa);
          xa = fmaf(wrow[d4 * 4 + 1], xv.y, xa);
          xa = fmaf(wrow[d4 * 4 + 2], xv.z, xa);
          xa = fmaf(wrow[d4 * 4 + 3], xv.w, xa);
        }
        LP[XPRE_F + xr * 17 + b] = xa;
      }
    } else if (tid < 16) {
      LP[XLAST_F + tid] = x[((size_t)(bg0 + tid) * 512 + tt) * 64 + 63];
    }
  };

  auto flag_addr = [&](int i) -> unsigned* { return &flags[(size_t)((g << 5) + i) * FLAG_STRIDE]; };
  auto flag_put = [&](unsigned tgt_epoch) {
    if (mode == 2)
      __hip_atomic_fetch_add(flag_addr(s), 1u, __ATOMIC_RELAXED, __HIP_MEMORY_SCOPE_WORKGROUP);
    else
      __hip_atomic_store(flag_addr(s), tgt_epoch, __ATOMIC_RELAXED, __HIP_MEMORY_SCOPE_AGENT);
  };
  // Per-lane-exit poll: lanes 0..31 each watch one producer; a satisfied lane exits the loop
  // (exec-masked off) and stops issuing RMWs.
  auto flag_poll = [&](unsigned tgt_epoch) {
    if (lane < NSL) {
      int cnt = 0;
      while (true) {
        unsigned v;
        if (mode == 2)
          v = __hip_atomic_fetch_add(flag_addr(lane), 0x10000u, __ATOMIC_RELAXED,
                                     __HIP_MEMORY_SCOPE_WORKGROUP) & 0xFFFFu;
        else
          v = __hip_atomic_load(flag_addr(lane), __ATOMIC_RELAXED, __HIP_MEMORY_SCOPE_AGENT);
        if (v >= tgt_epoch) break;
        __builtin_amdgcn_s_sleep(1);
        if (++cnt > 300000) break;   // escape hatch: wrong answer instead of hang
      }
    }
  };

  stage_x(0);
  asm volatile("s_waitcnt vmcnt(0)" ::: "memory");
  __syncthreads();
  if (tid == 0) flag_put(1u);
  if (wv == 7) flag_poll(1u);
  __syncthreads();

  const unsigned short* ah16 = (const unsigned short*)smem;

  for (int t = 0; t <= 512; ++t) {
    const bool last = (t == 512);
    const bool teacher = (!last) && (MSK[t] != 0);
    const int csel = teacher ? 1 : 2;
    const char* src = data + (size_t)(hist ? t : (t & 1)) * STEP_BYTES + (size_t)g * GRP_BYTES;

    // -------- phase A: fetch 32KB h(t) image into LDS (identity copy) --------
    if (mode == 0) {
      u64 a0[4], a1[4];
#pragma unroll
      for (int i = 0; i < 4; ++i) {
        const u64* p = (const u64*)(src + (size_t)(i * 512 + tid) * 16);
        a0[i] = __hip_atomic_load(p,     __ATOMIC_RELAXED, __HIP_MEMORY_SCOPE_AGENT);
        a1[i] = __hip_atomic_load(p + 1, __ATOMIC_RELAXED, __HIP_MEMORY_SCOPE_AGENT);
      }
#pragma unroll
      for (int i = 0; i < 4; ++i) {
        u64* d = (u64*)(smem + (size_t)(i * 512 + tid) * 16);
        d[0] = a0[i]; d[1] = a1[i];
      }
    } else {
      uint4 v[4];
#pragma unroll
      for (int i = 0; i < 4; ++i) v[i] = *(const uint4*)(src + (size_t)(i * 512 + tid) * 16);
#pragma unroll
      for (int i = 0; i < 4; ++i) *(uint4*)(smem + (size_t)(i * 512 + tid) * 16) = v[i];
    }
    __syncthreads();   // sync A

    // -------- MFMA (waves 0-5): ct0 always, ct1 teacher, ct2 AR; 2 col-tiles each --------
    if (!last && wv < 6 && (myct == 0 || myct == csel)) {
      const int slot = (myct == 0) ? 0 : 1;
#pragma unroll
      for (int ti = 0; ti < 2; ++ti) {
        f32x4 acc0 = {0.f, 0.f, 0.f, 0.f};
        f32x4 acc1 = {0.f, 0.f, 0.f, 0.f};
        f32x4 acc2 = {0.f, 0.f, 0.f, 0.f};
        f32x4 acc3 = {0.f, 0.f, 0.f, 0.f};
#pragma unroll
        for (int i = 0; i < 8; ++i) {
          const char* abh = smem + (size_t)((mykh * 8 + i) * 1024) + lane * 16;
          bf16x8 ahh = *(const bf16x8*)abh;
          bf16x8 ahl = *(const bf16x8*)(abh + 16384);
          f32x4& acc = ((i & 3) == 0) ? acc0 : ((i & 3) == 1) ? acc1 : ((i & 3) == 2) ? acc2 : acc3;
          acc = __builtin_amdgcn_mfma_f32_16x16x32_bf16(ahh, Bh[ti * 8 + i], acc, 0, 0, 0);
          acc = __builtin_amdgcn_mfma_f32_16x16x32_bf16(ahh, Bl[ti * 8 + i], acc, 0, 0, 0);
          acc = __builtin_amdgcn_mfma_f32_16x16x32_bf16(ahl, Bh[ti * 8 + i], acc, 0, 0, 0);
        }
        f32x4 acc = (acc0 + acc1) + (acc2 + acc3);
        const int row = ti * 16 + (lane & 15);
        const int bcol = (lane >> 4) << 2;
#pragma unroll
        for (int q = 0; q < 4; ++q)
          LP[PREP_F + ((mykh * 2 + slot) * 32 + row) * 17 + bcol + q] = acc[q];
      }
    }

    // -------- out-dot (waves 6,7): 512 tasks = 2 dims x 16 b x 16 ks, 4/thread --------
    if (wv >= 6) {
#pragma unroll
      for (int tk = 0; tk < 4; ++tk) {
        const int task = (tid - 384) + tk * 128;
        const int d = task >> 8, rem = task & 255;
        const int b = rem & 15, ks = rem >> 4;
        const float* woc = &LP[WOC_F + d * 512];
        float oa = 0.f;
#pragma unroll
        for (int c = 0; c < 4; ++c) {
          const uint4 wh = *(const uint4*)(smem + (size_t)(ks * 1024) + (b | (c << 4)) * 16);
          const uint4 wl = *(const uint4*)(smem + (size_t)(16384 + ks * 1024) + (b | (c << 4)) * 16);
          int k0 = ks * 32 + c * 8;
          oa = fmaf(bfhilo(wh.x & 0xFFFFu, wl.x & 0xFFFFu), woc[k0 + 0], oa);
          oa = fmaf(bfhilo(wh.x >> 16, wl.x >> 16), woc[k0 + 1], oa);
          oa = fmaf(bfhilo(wh.y & 0xFFFFu, wl.y & 0xFFFFu), woc[k0 + 2], oa);
          oa = fmaf(bfhilo(wh.y >> 16, wl.y >> 16), woc[k0 + 3], oa);
          oa = fmaf(bfhilo(wh.z & 0xFFFFu, wl.z & 0xFFFFu), woc[k0 + 4], oa);
          oa = fmaf(bfhilo(wh.z >> 16, wl.z >> 16), woc[k0 + 5], oa);
          oa = fmaf(bfhilo(wh.w & 0xFFFFu, wl.w & 0xFFFFu), woc[k0 + 6], oa);
          oa = fmaf(bfhilo(wh.w >> 16, wl.w >> 16), woc[k0 + 7], oa);
        }
        LP[ORED_F + d * 272 + b * 17 + ks] = oa;
      }
    }
    __syncthreads();   // sync B

    if (!last) {
      // -------- gates (tid<256: b=tid&15, jj=tid>>4) -> shfl pack -> publish --------
      if (tid < 256) {
        const int b = tid & 15, jj = tid >> 4;
        const float* PR = &LP[PREP_F];
        float pr  = PR[(0 * 32 + jj) * 17 + b]        + PR[(2 * 32 + jj) * 17 + b];
        float pz  = PR[(0 * 32 + 16 + jj) * 17 + b]   + PR[(2 * 32 + 16 + jj) * 17 + b];
        float pnh = PR[(1 * 32 - 32 + jj) * 17 + b];  // placeholder, recomputed below
        // PREP slots: index (kh*2+slot): kh0slot0=0, kh0slot1=1, kh1slot0=2, kh1slot1=3
        pr  = PR[(1 * 32 + jj) * 17 + b]      + PR[(3 * 32 + jj) * 17 + b];
        pz  = PR[(1 * 32 + 16 + jj) * 17 + b] + PR[(3 * 32 + 16 + jj) * 17 + b];
        pnh = PR[(0 * 32 + jj) * 17 + b]      + PR[(2 * 32 + jj) * 17 + b] + LP[SB_F + 96 + jj];
        float pni;
        if (teacher) {
          pr += LP[XPRE_F + jj * 17 + b] + LP[SB_F + jj];
          pz += LP[XPRE_F + (16 + jj) * 17 + b] + LP[SB_F + 16 + jj];
          pni = LP[XPRE_F + (32 + jj) * 17 + b] + LP[SB_F + 112 + jj];
        } else {
          float xl = LP[XLAST_F + b];
          pr += LP[SB_F + 32 + jj] + LP[SB_F + 64 + jj] * xl;
          pz += LP[SB_F + 48 + jj] + LP[SB_F + 80 + jj] * xl;
          pni = PR[(0 * 32 + 16 + jj) * 17 + b] + PR[(2 * 32 + 16 + jj) * 17 + b]
              + LP[SB_F + 128 + jj] + LP[SB_F + 144 + jj] * xl;
        }
        const int cc = (2 * s + (jj >> 3)) & 3;
        const int e = jj & 7;
        size_t hoff = (size_t)ks0 * 1024 + (size_t)(b | (cc << 4)) * 16 + (size_t)e * 2;
        float hp = bfhilo(ah16[hoff >> 1], ah16[(hoff + 16384) >> 1]);
        float rg = 1.f / (1.f + expf(-pr));
        float zg = 1.f / (1.f + expf(-pz));
        float ng = tanhf(fmaf(rg, pnh, pni));
        float hv = fmaf(zg, hp - ng, ng);
        float hvp = __shfl_xor(hv, 16, 64);   // partner jj^1, same batch
        if ((jj & 1) == 0) {
          unsigned h0h = rne16(hv), h1h = rne16(hvp);
          float r0 = hv  - __uint_as_float(h0h << 16);
          float r1 = hvp - __uint_as_float(h1h << 16);
          unsigned hw = h0h | (h1h << 16);
          unsigned lw = rne16(r0) | (rne16(r1) << 16);
          char* dst = data + (size_t)(hist ? (t + 1) : ((t + 1) & 1)) * STEP_BYTES
                    + (size_t)g * GRP_BYTES;
          unsigned* dhh = (unsigned*)(dst + hoff);
          unsigned* dhl = (unsigned*)(dst + 16384 + hoff);
          if (mode == 2) {
            *(volatile unsigned*)dhh = hw;
            *(volatile unsigned*)dhl = lw;
          } else {
            __hip_atomic_store(dhh, hw, __ATOMIC_RELAXED, __HIP_MEMORY_SCOPE_AGENT);
            __hip_atomic_store(dhl, lw, __ATOMIC_RELAXED, __HIP_MEMORY_SCOPE_AGENT);
          }
        }
      }
      // -------- barrier: drain, arrive, hidden work, poll (per-lane exit), release --------
      asm volatile("s_waitcnt vmcnt(0)" ::: "memory");
      __syncthreads();   // sync C
      const unsigned tgt = (unsigned)(t + 2);
      if (tid == 0) flag_put(tgt);
      if (t >= 1 && tid >= 256 && tid < 288) {
        const int q = tid - 256, b = q & 15, d = q >> 4;
        float o = LP[SB_F + 160 + d];
#pragma unroll
        for (int i = 0; i < 16; ++i) o += LP[ORED_F + d * 272 + b * 17 + i];
        out[((size_t)(bg0 + b) * 512 + (t - 1)) * 64 + 2 * s + d] = o;
      }
      stage_x(t + 1);
      if (wv == 7) flag_poll(tgt);
      __syncthreads();   // sync D
    } else {
      if (tid >= 256 && tid < 288) {
        const int q = tid - 256, b = q & 15, d = q >> 4;
        float o = LP[SB_F + 160 + d];
#pragma unroll
        for (int i = 0; i < 16; ++i) o += LP[ORED_F + d * 272 + b * 17 + i];
        out[((size_t)(bg0 + b) * 512 + 511) * 64 + 2 * s + d] = o;
      }
    }
  }
}

extern "C" void kernel_launch(void* const* d_in, const int* in_sizes, int n_in,
                              void* d_out, int out_size, void* d_ws, size_t ws_size,
                              hipStream_t stream) {
  (void)in_sizes; (void)n_in; (void)out_size;
  const float* x    = (const float*)d_in[0];
  const float* tp   = (const float*)d_in[1];
  const int*   mask = (const int*)d_in[2];
  const float* W_ih = (const float*)d_in[3];
  const float* W_hh = (const float*)d_in[4];
  const float* b_ih = (const float*)d_in[5];
  const float* b_hh = (const float*)d_in[6];
  const float* W_out= (const float*)d_in[7];
  const float* b_out= (const float*)d_in[8];
  float* out = (float*)d_out;
  if (ws_size < FB_NEEDED) return;
  int hist = (ws_size >= HIST_NEEDED) ? 1 : 0;
  hipMemsetAsync(d_ws, 0, CTRL_BYTES, stream);
  hipFuncSetAttribute((const void*)gru_persistent,
                      hipFuncAttributeMaxDynamicSharedMemorySize, LDS_BYTES);
  hipLaunchKernelGGL(gru_persistent, dim3(NWG), dim3(TB), LDS_BYTES, stream,
                     x, tp, mask, W_ih, W_hh, b_ih, b_hh, W_out, b_out,
                     (char*)d_ws, out, hist);
}